// Round 3
// baseline (1036.711 us; speedup 1.0000x reference)
//
#include <hip/hip_runtime.h>
#include <hip/hip_bf16.h>
#include <math.h>

// Problem constants
#define B_  16
#define N_  256
#define D_  512
#define H_  8
#define NL_ 2
#define dh_ 64
#define D4_ 2048
#define BN_ (B_ * N_)           // 4096 tokens
#define BND_ ((size_t)BN_ * D_) // 2,097,152 floats

// ---------------------------------------------------------------------------
// RMSNorm over last dim D=512. One block (256 thr) per row.
__global__ __launch_bounds__(256)
void rms_kernel(const float* __restrict__ x, const float* __restrict__ w,
                float* __restrict__ out, float eps) {
    int row = blockIdx.x;
    const float* xr = x + (size_t)row * D_;
    int t = threadIdx.x;
    float v0 = xr[t], v1 = xr[t + 256];
    float s = v0 * v0 + v1 * v1;
    #pragma unroll
    for (int o = 32; o > 0; o >>= 1) s += __shfl_down(s, o);
    __shared__ float wsum[4];
    __shared__ float scale_sh;
    int lane = t & 63, wv = t >> 6;
    if (lane == 0) wsum[wv] = s;
    __syncthreads();
    if (t == 0) {
        float tot = wsum[0] + wsum[1] + wsum[2] + wsum[3];
        scale_sh = rsqrtf(tot * (1.0f / D_) + eps);
    }
    __syncthreads();
    float sc = scale_sh;
    float* orow = out + (size_t)row * D_;
    orow[t]       = v0 * sc * w[t];
    orow[t + 256] = v1 * sc * w[t + 256];
}

// ---------------------------------------------------------------------------
// Shared GEMM core: 128x64 tile, BK=16, 256 threads, 8x4 microtile,
// all-float4 LDS traffic, register-prefetch software pipeline so the
// global-load latency of k-block kb+1 hides under the FMA body of kb.
// A is row-major [M x K] (tile kept [m][k], staging = contiguous float4s);
// W is row-major [K x Nc].
__device__ __forceinline__ void gemm_core(const float* __restrict__ A,
                                          const float* __restrict__ W,
                                          int Nc, int K, int row0, int col0,
                                          float acc[8][4]) {
    __shared__ float As[128][16];   // [m][k]
    __shared__ float Bs[16][64];    // [k][n]
    int tid = threadIdx.x;
    int tx = tid & 15;              // col group: cols tx*4 .. tx*4+3
    int ty = tid >> 4;              // row group: rows ty*8 .. ty*8+7

    // staging indices
    int arow = tid >> 1;            // 0..127
    int ak   = (tid & 1) * 8;       // 0 or 8
    int bk   = tid >> 4;            // 0..15
    int bc   = (tid & 15) * 4;
    const float* Aptr = A + (size_t)(row0 + arow) * K + ak;
    const float* Wptr = W + (size_t)bk * Nc + col0 + bc;

    // preload k-block 0
    float4 a0 = *(const float4*)(Aptr);
    float4 a1 = *(const float4*)(Aptr + 4);
    float4 bv = *(const float4*)(Wptr);

    for (int kb = 0; kb < K; kb += 16) {
        __syncthreads();            // previous-iter compute done; LDS free
        *(float4*)&As[arow][ak]     = a0;
        *(float4*)&As[arow][ak + 4] = a1;
        *(float4*)&Bs[bk][bc]       = bv;
        __syncthreads();

        if (kb + 16 < K) {          // prefetch next k-block; latency hides
            Aptr += 16;             // under the FMA body below
            Wptr += (size_t)16 * Nc;
            a0 = *(const float4*)(Aptr);
            a1 = *(const float4*)(Aptr + 4);
            bv = *(const float4*)(Wptr);
        }

        #pragma unroll
        for (int kg = 0; kg < 4; ++kg) {
            float4 a[8];
            #pragma unroll
            for (int i = 0; i < 8; ++i)
                a[i] = *(const float4*)&As[ty * 8 + i][kg * 4];
            float4 b[4];
            #pragma unroll
            for (int j2 = 0; j2 < 4; ++j2)
                b[j2] = *(const float4*)&Bs[kg * 4 + j2][tx * 4];
            #pragma unroll
            for (int i = 0; i < 8; ++i) {
                float av[4] = {a[i].x, a[i].y, a[i].z, a[i].w};
                #pragma unroll
                for (int j2 = 0; j2 < 4; ++j2) {
                    acc[i][0] += av[j2] * b[j2].x;
                    acc[i][1] += av[j2] * b[j2].y;
                    acc[i][2] += av[j2] * b[j2].z;
                    acc[i][3] += av[j2] * b[j2].w;
                }
            }
        }
    }
}

// ---------------------------------------------------------------------------
// MLP GEMMs. MODE 1: exact gelu   MODE 2: + bias[col] + resid[row,col]
template<int MODE>
__global__ __launch_bounds__(256)
void gemm_kernel(const float* __restrict__ A, const float* __restrict__ W,
                 float* __restrict__ C, const float* __restrict__ bias,
                 const float* __restrict__ resid, int M, int Nc, int K) {
    int tid = threadIdx.x;
    int tx = tid & 15, ty = tid >> 4;
    int row0 = blockIdx.y * 128, col0 = blockIdx.x * 64;
    float acc[8][4] = {};
    gemm_core(A, W, Nc, K, row0, col0, acc);

    float4 bs4;
    if (MODE == 2) bs4 = *(const float4*)&bias[col0 + tx * 4];
    #pragma unroll
    for (int i = 0; i < 8; ++i) {
        size_t row = row0 + ty * 8 + i;
        float v0 = acc[i][0], v1 = acc[i][1], v2 = acc[i][2], v3 = acc[i][3];
        if (MODE == 1) {
            const float r2 = 0.70710678118654752f;
            v0 = 0.5f * v0 * (1.0f + erff(v0 * r2));
            v1 = 0.5f * v1 * (1.0f + erff(v1 * r2));
            v2 = 0.5f * v2 * (1.0f + erff(v2 * r2));
            v3 = 0.5f * v3 * (1.0f + erff(v3 * r2));
        } else if (MODE == 2) {
            float4 rv = *(const float4*)&resid[row * Nc + col0 + tx * 4];
            v0 += bs4.x + rv.x;
            v1 += bs4.y + rv.y;
            v2 += bs4.z + rv.z;
            v3 += bs4.w + rv.w;
        }
        *(float4*)&C[row * Nc + col0 + tx * 4] = make_float4(v0, v1, v2, v3);
    }
}

// ---------------------------------------------------------------------------
// All 4 Q/V projections in one launch, with the per-head RMSNorm fused into
// the epilogue. grid = (8, 32, 4); z = layer*2 + (0=Q,1=V). The 64-col tile
// spans exactly one head (Nc=512, tile 64), so each row's complete head
// vector is in this tile's acc: row sum-of-squares = 4 local squares +
// 4 shfl_xor across the 16 lanes sharing the row.
__global__ __launch_bounds__(256)
void qv_gemm_kernel(const float* __restrict__ xorig,
                    const float* __restrict__ q_w, const float* __restrict__ v_w,
                    const float* __restrict__ qn_w, const float* __restrict__ vn_w,
                    float* __restrict__ qbuf, float* __restrict__ vbuf) {
    int z   = blockIdx.z;
    int lyr = z >> 1, isv = z & 1;
    const float* W  = (isv ? v_w : q_w) + (size_t)lyr * D_ * D_;
    float*       C  = (isv ? vbuf : qbuf) + (size_t)lyr * BND_;
    const float* nw = (isv ? vn_w : qn_w) + (size_t)lyr * H_ * dh_
                      + (size_t)blockIdx.x * dh_;      // head = blockIdx.x

    int tid = threadIdx.x;
    int tx = tid & 15, ty = tid >> 4;
    int row0 = blockIdx.y * 128, col0 = blockIdx.x * 64;
    float acc[8][4] = {};
    gemm_core(xorig, W, D_, D_, row0, col0, acc);

    float4 wn4 = *(const float4*)&nw[tx * 4];
    #pragma unroll
    for (int i = 0; i < 8; ++i) {
        float ss = acc[i][0] * acc[i][0] + acc[i][1] * acc[i][1]
                 + acc[i][2] * acc[i][2] + acc[i][3] * acc[i][3];
        ss += __shfl_xor(ss, 1);
        ss += __shfl_xor(ss, 2);
        ss += __shfl_xor(ss, 4);
        ss += __shfl_xor(ss, 8);
        float sc = rsqrtf(ss * (1.0f / dh_) + 1e-8f);
        size_t row = row0 + ty * 8 + i;
        float4 o = make_float4(acc[i][0] * sc * wn4.x, acc[i][1] * sc * wn4.y,
                               acc[i][2] * sc * wn4.z, acc[i][3] * sc * wn4.w);
        *(float4*)&C[row * D_ + col0 + tx * 4] = o;
    }
}

// ---------------------------------------------------------------------------
// S = (tril(LU,-1)+I) @ (triu(LU,1)+I*softplus(diag)). One block per head.
__device__ __forceinline__ float um_elem(const float lu[64][64], int k, int c) {
    if (c > k) return lu[k][c];
    if (c == k) return log1pf(expf(lu[k][k]));
    return 0.0f;
}

__global__ __launch_bounds__(256)
void smat_kernel(const float* __restrict__ LU, float* __restrict__ S) {
    int h = blockIdx.x;
    __shared__ float lu[64][64];
    const float* src = LU + (size_t)h * 4096;
    for (int i = threadIdx.x; i < 4096; i += 256) lu[i >> 6][i & 63] = src[i];
    __syncthreads();
    int r  = threadIdx.x >> 2;
    int c0 = (threadIdx.x & 3) * 16;
    for (int cc = 0; cc < 16; ++cc) {
        int c = c0 + cc;
        float acc = um_elem(lu, r, c);          // k == r term (Lm[r][r] = 1)
        for (int k = 0; k < r; ++k) acc += lu[r][k] * um_elem(lu, k, c);
        S[(size_t)h * 4096 + r * 64 + c] = acc;
    }
}

// ---------------------------------------------------------------------------
// Linear-attention causal scan. One block (4 waves) per (b,h).
// Wave w owns state cols 16w..16w+15; lane owns 16 rows x 1 col:
//   col = ((tid>>6)<<4) | (tid&15),  rows r0..r0+15 with r0 = ((tid>>4)&3)*16.
// Q.W reduction over the 4 row groups = 2 x shfl_xor (no LDS, no barrier).
// FIRST=1: writes xout (layer-1 K input) and initializes ares;
// FIRST=0: no xout, accumulates ares.
template<int FIRST>
__global__ __launch_bounds__(256)
void attn_kernel(const float* __restrict__ Kp, const float* __restrict__ Qp,
                 const float* __restrict__ Vp, float* __restrict__ xout,
                 float* __restrict__ ares) {
    int b = blockIdx.x >> 3, h = blockIdx.x & 7;
    int tid = threadIdx.x;
    int col = ((tid >> 6) << 4) | (tid & 15);
    int rg  = (tid >> 4) & 3;
    int r0  = rg * 16;
    float w[16] = {};
    __shared__ float Ks[16][64], Qs[16][64], Vs[16][64];
    const size_t base = ((size_t)b * N_) * D_ + h * dh_;
    const float* kbp = Kp + base;
    const float* qbp = Qp + base;
    const float* vbp = Vp + base;
    float* xo = xout ? xout + base : nullptr;
    float* ar = ares + (size_t)b * (N_ / 2) * D_ + h * dh_;
    int sp = tid >> 4;          // stage position 0..15
    int sc = (tid & 15) * 4;    // stage column

    for (int l0 = 0; l0 < N_; l0 += 16) {
        size_t so = (size_t)(l0 + sp) * D_ + sc;
        *(float4*)&Ks[sp][sc] = *(const float4*)(kbp + so);
        *(float4*)&Qs[sp][sc] = *(const float4*)(qbp + so);
        *(float4*)&Vs[sp][sc] = *(const float4*)(vbp + so);
        __syncthreads();
        #pragma unroll 4
        for (int ll = 0; ll < 16; ++ll) {
            float vc = Vs[ll][col];
            float p0 = 0.f, p1 = 0.f, p2 = 0.f, p3 = 0.f;
            #pragma unroll
            for (int g = 0; g < 4; ++g) {
                float4 kf = *(const float4*)&Ks[ll][r0 + g * 4];
                float4 qf = *(const float4*)&Qs[ll][r0 + g * 4];
                w[g*4+0] += kf.x * vc;  p0 += qf.x * w[g*4+0];
                w[g*4+1] += kf.y * vc;  p1 += qf.y * w[g*4+1];
                w[g*4+2] += kf.z * vc;  p2 += qf.z * w[g*4+2];
                w[g*4+3] += kf.w * vc;  p3 += qf.w * w[g*4+3];
            }
            float partial = (p0 + p1) + (p2 + p3);
            partial += __shfl_xor(partial, 16);
            partial += __shfl_xor(partial, 32);
            if (rg == 0) {
                int l = l0 + ll;
                if (FIRST) xo[(size_t)l * D_ + col] = partial;
                if (l & 1) {
                    size_t ai = (size_t)(l >> 1) * D_ + col;
                    if (FIRST) ar[ai] = partial;
                    else       ar[ai] += partial;
                }
            }
        }
        __syncthreads();
    }
}

// ---------------------------------------------------------------------------
// out[b,n2,:] = x_orig[b,2*n2+1,:] + per-head (attn_res[b,n2,h,:] @ S[h])
__global__ __launch_bounds__(256)
void final_kernel(const float* __restrict__ xorig, const float* __restrict__ ares,
                  const float* __restrict__ S, float* __restrict__ out) {
    int row = blockIdx.x;               // 0 .. B*(N/2)-1
    int b = row >> 7, n2 = row & 127;   // N/2 = 128
    int tid = threadIdx.x;
    __shared__ float a[512];
    const float* ar = ares + (size_t)row * D_;
    a[tid] = ar[tid];
    a[tid + 256] = ar[tid + 256];
    __syncthreads();
    const float* xo = xorig + ((size_t)b * N_ + 2 * n2 + 1) * D_;
    #pragma unroll
    for (int rep = 0; rep < 2; ++rep) {
        int eg = tid + rep * 256;
        int h = eg >> 6, e = eg & 63;
        const float* Sh = S + (size_t)h * 4096;
        const float* ah = a + h * dh_;
        float acc = 0.0f;
        #pragma unroll 8
        for (int dd = 0; dd < 64; ++dd) acc += ah[dd] * Sh[dd * 64 + e];
        out[(size_t)row * D_ + eg] = xo[eg] + acc;
    }
}

// ---------------------------------------------------------------------------
extern "C" void kernel_launch(void* const* d_in, const int* in_sizes, int n_in,
                              void* d_out, int out_size, void* d_ws, size_t ws_size,
                              hipStream_t stream) {
    const float* x_in  = (const float*)d_in[0];
    const float* ln_w  = (const float*)d_in[1];
    const float* fc_w  = (const float*)d_in[2];
    const float* fc2_w = (const float*)d_in[3];
    const float* fc2_b = (const float*)d_in[4];
    const float* var_w = (const float*)d_in[5];
    const float* q_w   = (const float*)d_in[6];
    const float* v_w   = (const float*)d_in[7];
    const float* qn_w  = (const float*)d_in[8];
    const float* vn_w  = (const float*)d_in[9];
    const float* LU    = (const float*)d_in[10];
    float* out = (float*)d_out;
    float* ws  = (float*)d_ws;

    // workspace layout (floats), compacted via reuse:
    //   gbuf (4 BND) dead after MLP -> reused for qbuf/vbuf
    //   hbuf dead after var-RMS     -> reused for xabuf
    float* xbuf  = ws;                        // BND
    float* hbuf  = ws + BND_;                 // BND
    float* gbuf  = ws + 2 * BND_;             // 4*BND (BN x 2048)
    float* xorig = ws + 6 * BND_;             // BND
    float* arbuf = ws + 7 * BND_;             // BND/2
    float* Sbuf  = ws + 7 * BND_ + BND_ / 2;  // H*64*64
    float* qbuf  = gbuf;                      // 2*BND (NL layers)
    float* vbuf  = gbuf + 2 * BND_;           // 2*BND
    float* xabuf = hbuf;                      // BND

    dim3 blk(256);
    dim3 g_rows(BN_);                          // rms
    dim3 g_fc1(D4_ / 64, BN_ / 128);           // 32 x 32
    dim3 g_fc2(D_ / 64, BN_ / 128);            // 8 x 32
    dim3 g_qv(D_ / 64, BN_ / 128, 4);          // 8 x 32 x 4

    // --- pre-MLP stack ---
    for (int i = 0; i < NL_; ++i) {
        const float* src   = (i == 0) ? x_in : xbuf;
        const float* resid = src;
        rms_kernel<<<g_rows, blk, 0, stream>>>(src, ln_w + i * D_, hbuf, 1e-5f);
        gemm_kernel<1><<<g_fc1, blk, 0, stream>>>(hbuf, fc_w + (size_t)i * D_ * D4_,
                                                  gbuf, nullptr, nullptr,
                                                  BN_, D4_, D_);
        gemm_kernel<2><<<g_fc2, blk, 0, stream>>>(gbuf, fc2_w + (size_t)i * D4_ * D_,
                                                  xbuf, fc2_b + i * D_, resid,
                                                  BN_, D_, D4_);
    }

    // --- var RMS -> x_orig ---
    rms_kernel<<<g_rows, blk, 0, stream>>>(xbuf, var_w, xorig, 1e-5f);

    // --- S = L @ U ---
    smat_kernel<<<dim3(H_), blk, 0, stream>>>(LU, Sbuf);

    // --- all 4 Q/V projections + fused per-head RMS in ONE launch ---
    qv_gemm_kernel<<<g_qv, blk, 0, stream>>>(xorig, q_w, v_w, qn_w, vn_w,
                                             qbuf, vbuf);

    // --- stacked linear attention (layer 1's K is layer 0's output) ---
    dim3 g_attn(B_ * H_);
    attn_kernel<1><<<g_attn, blk, 0, stream>>>(xorig, qbuf, vbuf, xabuf, arbuf);
    attn_kernel<0><<<g_attn, blk, 0, stream>>>(xabuf, qbuf + BND_, vbuf + BND_,
                                               nullptr, arbuf);

    // --- final: x_orig odd rows + attn_res @ S ---
    final_kernel<<<dim3(B_ * N_ / 2), blk, 0, stream>>>(xorig, arbuf, Sbuf, out);
}

// Round 7
// 589.261 us; speedup vs baseline: 1.7593x; 1.7593x over previous
//
#include <hip/hip_runtime.h>
#include <hip/hip_bf16.h>
#include <math.h>

// Problem constants
#define B_  16
#define N_  256
#define D_  512
#define H_  8
#define NL_ 2
#define dh_ 64
#define D4_ 2048
#define BN_ (B_ * N_)           // 4096 tokens
#define BND_ ((size_t)BN_ * D_) // 2,097,152 floats

typedef float f32x4  __attribute__((ext_vector_type(4)));
typedef short bf16x8 __attribute__((ext_vector_type(8)));

// ---------------------------------------------------------------------------
// fp32 -> bf16 helpers for exact 3-term split: a = hi + lo, hi = trunc-bf16,
// lo = rne-bf16(a - hi)  (a - hi is exact in fp32).
__device__ __forceinline__ unsigned bf16rne(float f) {
    unsigned u = __float_as_uint(f);
    return (u + 0x7FFFu + ((u >> 16) & 1u)) >> 16;
}
__device__ __forceinline__ void cvt4(float4 v, uint2& hi, uint2& lo) {
    unsigned ux = __float_as_uint(v.x), uy = __float_as_uint(v.y);
    unsigned uz = __float_as_uint(v.z), uw = __float_as_uint(v.w);
    hi.x = (ux >> 16) | (uy & 0xFFFF0000u);
    hi.y = (uz >> 16) | (uw & 0xFFFF0000u);
    float rx = v.x - __uint_as_float(ux & 0xFFFF0000u);
    float ry = v.y - __uint_as_float(uy & 0xFFFF0000u);
    float rz = v.z - __uint_as_float(uz & 0xFFFF0000u);
    float rw = v.w - __uint_as_float(uw & 0xFFFF0000u);
    lo.x = bf16rne(rx) | (bf16rne(ry) << 16);
    lo.y = bf16rne(rz) | (bf16rne(rw) << 16);
}

// ---------------------------------------------------------------------------
// Split-bf16 MFMA GEMM core. 128x128 tile, BK=32, 256 thr (4 waves, 2x2).
// Per wave 64x64 out = 4x4 frags of mfma_f32_16x16x32_bf16; 3 products
// (hi*hi + hi*lo + lo*hi) in fp32 accumulators. LDS: bf16 planes As[m][k],
// Bs[n][k], rows padded to 40 shorts. A staging: vector writes (bank floor).
// B staging: thread owns k=(tid&7)*4+e, n=(tid>>3)*4+j; transpose via b64
// writes whose banks hit the structural floor (no >=4-way conflicts).
// Register prefetch hides global latency of step kb+32 under the MFMAs.
// EPI: 0 = plain store, 1 = exact gelu, 2 = atomicAdd into C.
#define PADK 40
template<int EPI>
__device__ __forceinline__ void mfma_core(const float* __restrict__ A,
                                          const float* __restrict__ W,
                                          float* __restrict__ C,
                                          int lda, int ldw,
                                          int row0, int col0,
                                          int kbeg, int kend) {
    __shared__ __align__(16) short As_hi[128][PADK];
    __shared__ __align__(16) short As_lo[128][PADK];
    __shared__ __align__(16) short Bs_hi[128][PADK];
    __shared__ __align__(16) short Bs_lo[128][PADK];

    int tid  = threadIdx.x;
    int lane = tid & 63;
    int wid  = tid >> 6;
    int wrow = (wid >> 1) * 64;
    int wcol = (wid & 1) * 64;
    int r16  = lane & 15;
    int kg8  = (lane >> 4) * 8;

    // staging indices
    int arow = tid >> 1, ak0 = (tid & 1) * 16;   // A: 16 contiguous k
    int bk4  = (tid & 7) * 4;                    // B: k base (4 rows)
    int bn4  = (tid >> 3) * 4;                   // B: n base (4 cols)
    const float* Ap = A + (size_t)(row0 + arow) * lda + kbeg + ak0;
    const float* Wp = W + (size_t)(kbeg + bk4) * ldw + col0 + bn4;

    float4 af[4], wf[4];
    #pragma unroll
    for (int u = 0; u < 4; ++u) {
        af[u] = *(const float4*)(Ap + 4 * u);
        wf[u] = *(const float4*)(Wp + (size_t)u * ldw);
    }

    f32x4 acc[4][4];
    #pragma unroll
    for (int mf = 0; mf < 4; ++mf)
        #pragma unroll
        for (int nf = 0; nf < 4; ++nf)
            #pragma unroll
            for (int r = 0; r < 4; ++r) acc[mf][nf][r] = 0.0f;

    for (int kb = kbeg; kb < kend; kb += 32) {
        __syncthreads();            // previous compute done; LDS reusable
        // --- A: convert + packed vector writes (hi/lo) ---
        {
            uint2 h[4], l[4];
            #pragma unroll
            for (int u = 0; u < 4; ++u) cvt4(af[u], h[u], l[u]);
            *(uint4*)&As_hi[arow][ak0]     = make_uint4(h[0].x, h[0].y, h[1].x, h[1].y);
            *(uint4*)&As_hi[arow][ak0 + 8] = make_uint4(h[2].x, h[2].y, h[3].x, h[3].y);
            *(uint4*)&As_lo[arow][ak0]     = make_uint4(l[0].x, l[0].y, l[1].x, l[1].y);
            *(uint4*)&As_lo[arow][ak0 + 8] = make_uint4(l[2].x, l[2].y, l[3].x, l[3].y);
        }
        // --- B: transpose via per-column b64 writes (bank-floor pattern) ---
        #pragma unroll
        for (int j = 0; j < 4; ++j) {
            float4 colv = make_float4(((const float*)&wf[0])[j],
                                      ((const float*)&wf[1])[j],
                                      ((const float*)&wf[2])[j],
                                      ((const float*)&wf[3])[j]);
            uint2 h, l;
            cvt4(colv, h, l);
            *(uint2*)&Bs_hi[bn4 + j][bk4] = h;   // k = bk4..bk4+3
            *(uint2*)&Bs_lo[bn4 + j][bk4] = l;
        }
        __syncthreads();

        if (kb + 32 < kend) {       // prefetch next k-block into regs
            Ap += 32;
            Wp += (size_t)32 * ldw;
            #pragma unroll
            for (int u = 0; u < 4; ++u) {
                af[u] = *(const float4*)(Ap + 4 * u);
                wf[u] = *(const float4*)(Wp + (size_t)u * ldw);
            }
        }

        // --- fragments + 3-term MFMA ---
        bf16x8 ah[4], bh[4], tt[4];
        #pragma unroll
        for (int q = 0; q < 4; ++q)
            ah[q] = *(const bf16x8*)&As_hi[wrow + q * 16 + r16][kg8];
        #pragma unroll
        for (int q = 0; q < 4; ++q)
            bh[q] = *(const bf16x8*)&Bs_hi[wcol + q * 16 + r16][kg8];
        #pragma unroll
        for (int mf = 0; mf < 4; ++mf)
            #pragma unroll
            for (int nf = 0; nf < 4; ++nf)
                acc[mf][nf] = __builtin_amdgcn_mfma_f32_16x16x32_bf16(
                    ah[mf], bh[nf], acc[mf][nf], 0, 0, 0);
        #pragma unroll
        for (int q = 0; q < 4; ++q)
            tt[q] = *(const bf16x8*)&Bs_lo[wcol + q * 16 + r16][kg8];
        #pragma unroll
        for (int mf = 0; mf < 4; ++mf)
            #pragma unroll
            for (int nf = 0; nf < 4; ++nf)
                acc[mf][nf] = __builtin_amdgcn_mfma_f32_16x16x32_bf16(
                    ah[mf], tt[nf], acc[mf][nf], 0, 0, 0);
        #pragma unroll
        for (int q = 0; q < 4; ++q)
            tt[q] = *(const bf16x8*)&As_lo[wrow + q * 16 + r16][kg8];
        #pragma unroll
        for (int mf = 0; mf < 4; ++mf)
            #pragma unroll
            for (int nf = 0; nf < 4; ++nf)
                acc[mf][nf] = __builtin_amdgcn_mfma_f32_16x16x32_bf16(
                    tt[mf], bh[nf], acc[mf][nf], 0, 0, 0);
    }

    // --- epilogue: C/D layout col = lane&15, row = (lane>>4)*4 + r ---
    const float r2 = 0.70710678118654752f;
    int kg4 = (lane >> 4) * 4;
    #pragma unroll
    for (int mf = 0; mf < 4; ++mf)
        #pragma unroll
        for (int nf = 0; nf < 4; ++nf)
            #pragma unroll
            for (int r = 0; r < 4; ++r) {
                int row = row0 + wrow + mf * 16 + kg4 + r;
                int col = col0 + wcol + nf * 16 + r16;
                float v = acc[mf][nf][r];
                if (EPI == 1) v = 0.5f * v * (1.0f + erff(v * r2));
                if (EPI == 2) atomicAdd(&C[(size_t)row * ldw + col], v);
                else          C[(size_t)row * ldw + col] = v;
            }
}

// fc1 (EPI=1, gelu) / fc2 (EPI=2, atomic, z = K chunk of 512)
template<int EPI>
__global__ __launch_bounds__(256, 2)
void mfma_gemm(const float* __restrict__ A, const float* __restrict__ W,
               float* __restrict__ C, int lda, int ldw, int kchunk) {
    int kbeg = blockIdx.z * kchunk;
    mfma_core<EPI>(A, W, C, lda, ldw, blockIdx.y * 128, blockIdx.x * 128,
                   kbeg, kbeg + kchunk);
}

// Q/V projections: z = layer*2 + (0=Q,1=V); K = D.
__global__ __launch_bounds__(256, 2)
void qv_mfma_gemm(const float* __restrict__ xorig,
                  const float* __restrict__ q_w, const float* __restrict__ v_w,
                  float* __restrict__ qbuf, float* __restrict__ vbuf) {
    int z = blockIdx.z, lyr = z >> 1, isv = z & 1;
    const float* W = (isv ? v_w : q_w) + (size_t)lyr * D_ * D_;
    float*       C = (isv ? vbuf : qbuf) + (size_t)lyr * BND_;
    mfma_core<0>(xorig, W, C, D_, D_, blockIdx.y * 128, blockIdx.x * 128, 0, D_);
}

// ---------------------------------------------------------------------------
// RMSNorm over last dim D=512. One block (256 thr) per row.
__global__ __launch_bounds__(256)
void rms_kernel(const float* __restrict__ x, const float* __restrict__ w,
                float* __restrict__ out, float eps) {
    int row = blockIdx.x;
    const float* xr = x + (size_t)row * D_;
    int t = threadIdx.x;
    float v0 = xr[t], v1 = xr[t + 256];
    float s = v0 * v0 + v1 * v1;
    #pragma unroll
    for (int o = 32; o > 0; o >>= 1) s += __shfl_down(s, o);
    __shared__ float wsum[4];
    __shared__ float scale_sh;
    int lane = t & 63, wv = t >> 6;
    if (lane == 0) wsum[wv] = s;
    __syncthreads();
    if (t == 0) {
        float tot = wsum[0] + wsum[1] + wsum[2] + wsum[3];
        scale_sh = rsqrtf(tot * (1.0f / D_) + eps);
    }
    __syncthreads();
    float sc = scale_sh;
    float* orow = out + (size_t)row * D_;
    orow[t]       = v0 * sc * w[t];
    orow[t + 256] = v1 * sc * w[t + 256];
}

// ---------------------------------------------------------------------------
// Per-head RMSNorm (d=64), in place. One wave per (token, head).
__global__ __launch_bounds__(256)
void headrms_kernel(float* __restrict__ qv, const float* __restrict__ w, float eps) {
    int wid  = blockIdx.x * 4 + (threadIdx.x >> 6);
    int lane = threadIdx.x & 63;
    int token = wid >> 3;
    int h     = wid & 7;
    float* p = qv + (size_t)token * D_ + h * dh_;
    float v = p[lane];
    float s = v * v;
    #pragma unroll
    for (int o = 32; o > 0; o >>= 1) s += __shfl_down(s, o);
    s = __shfl(s, 0);
    float sc = rsqrtf(s * (1.0f / dh_) + eps);
    p[lane] = v * sc * w[h * dh_ + lane];
}

// ---------------------------------------------------------------------------
// xbuf = resid + bias (layer 0) or xbuf += bias (layer 1) before fc2 atomics.
__global__ __launch_bounds__(256)
void fc2init_kernel(const float* __restrict__ resid, const float* __restrict__ bias,
                    float* __restrict__ xb) {
    size_t i4 = (size_t)blockIdx.x * 256 + threadIdx.x;   // float4 index
    int col = (int)((i4 * 4) & (D_ - 1));
    float4 bb = *(const float4*)&bias[col];
    float4 r = resid ? ((const float4*)resid)[i4] : ((const float4*)xb)[i4];
    r.x += bb.x; r.y += bb.y; r.z += bb.z; r.w += bb.w;
    ((float4*)xb)[i4] = r;
}

// ---------------------------------------------------------------------------
// S = (tril(LU,-1)+I) @ (triu(LU,1)+I*softplus(diag)). One block per head.
__device__ __forceinline__ float um_elem(const float lu[64][64], int k, int c) {
    if (c > k) return lu[k][c];
    if (c == k) return log1pf(expf(lu[k][k]));
    return 0.0f;
}

__global__ __launch_bounds__(256)
void smat_kernel(const float* __restrict__ LU, float* __restrict__ S) {
    int h = blockIdx.x;
    __shared__ float lu[64][64];
    const float* src = LU + (size_t)h * 4096;
    for (int i = threadIdx.x; i < 4096; i += 256) lu[i >> 6][i & 63] = src[i];
    __syncthreads();
    int r  = threadIdx.x >> 2;
    int c0 = (threadIdx.x & 3) * 16;
    for (int cc = 0; cc < 16; ++cc) {
        int c = c0 + cc;
        float acc = um_elem(lu, r, c);
        for (int k = 0; k < r; ++k) acc += lu[r][k] * um_elem(lu, k, c);
        S[(size_t)h * 4096 + r * 64 + c] = acc;
    }
}

// ---------------------------------------------------------------------------
// Linear-attention causal scan. One block (4 waves) per (b,h).
// Wave w owns state cols 16w..16w+15; lane owns 16 rows x 1 col.
// Q.W reduction over the 4 row groups = 2 x shfl_xor (no LDS, no barrier).
template<int FIRST>
__global__ __launch_bounds__(256)
void attn_kernel(const float* __restrict__ Kp, const float* __restrict__ Qp,
                 const float* __restrict__ Vp, float* __restrict__ xout,
                 float* __restrict__ ares) {
    int b = blockIdx.x >> 3, h = blockIdx.x & 7;
    int tid = threadIdx.x;
    int col = ((tid >> 6) << 4) | (tid & 15);
    int rg  = (tid >> 4) & 3;
    int r0  = rg * 16;
    float w[16] = {};
    __shared__ float Ks[16][64], Qs[16][64], Vs[16][64];
    const size_t base = ((size_t)b * N_) * D_ + h * dh_;
    const float* kbp = Kp + base;
    const float* qbp = Qp + base;
    const float* vbp = Vp + base;
    float* xo = xout ? xout + base : nullptr;
    float* ar = ares + (size_t)b * (N_ / 2) * D_ + h * dh_;
    int sp = tid >> 4;
    int sc = (tid & 15) * 4;

    for (int l0 = 0; l0 < N_; l0 += 16) {
        size_t so = (size_t)(l0 + sp) * D_ + sc;
        *(float4*)&Ks[sp][sc] = *(const float4*)(kbp + so);
        *(float4*)&Qs[sp][sc] = *(const float4*)(qbp + so);
        *(float4*)&Vs[sp][sc] = *(const float4*)(vbp + so);
        __syncthreads();
        #pragma unroll 4
        for (int ll = 0; ll < 16; ++ll) {
            float vc = Vs[ll][col];
            float p0 = 0.f, p1 = 0.f, p2 = 0.f, p3 = 0.f;
            #pragma unroll
            for (int g = 0; g < 4; ++g) {
                float4 kf = *(const float4*)&Ks[ll][r0 + g * 4];
                float4 qf = *(const float4*)&Qs[ll][r0 + g * 4];
                w[g*4+0] += kf.x * vc;  p0 += qf.x * w[g*4+0];
                w[g*4+1] += kf.y * vc;  p1 += qf.y * w[g*4+1];
                w[g*4+2] += kf.z * vc;  p2 += qf.z * w[g*4+2];
                w[g*4+3] += kf.w * vc;  p3 += qf.w * w[g*4+3];
            }
            float partial = (p0 + p1) + (p2 + p3);
            partial += __shfl_xor(partial, 16);
            partial += __shfl_xor(partial, 32);
            if (rg == 0) {
                int l = l0 + ll;
                if (FIRST) xo[(size_t)l * D_ + col] = partial;
                if (l & 1) {
                    size_t ai = (size_t)(l >> 1) * D_ + col;
                    if (FIRST) ar[ai] = partial;
                    else       ar[ai] += partial;
                }
            }
        }
        __syncthreads();
    }
}

// ---------------------------------------------------------------------------
// out[b,n2,:] = x_orig[b,2*n2+1,:] + per-head (attn_res[b,n2,h,:] @ S[h])
__global__ __launch_bounds__(256)
void final_kernel(const float* __restrict__ xorig, const float* __restrict__ ares,
                  const float* __restrict__ S, float* __restrict__ out) {
    int row = blockIdx.x;
    int b = row >> 7, n2 = row & 127;
    int tid = threadIdx.x;
    __shared__ float a[512];
    const float* ar = ares + (size_t)row * D_;
    a[tid] = ar[tid];
    a[tid + 256] = ar[tid + 256];
    __syncthreads();
    const float* xo = xorig + ((size_t)b * N_ + 2 * n2 + 1) * D_;
    #pragma unroll
    for (int rep = 0; rep < 2; ++rep) {
        int eg = tid + rep * 256;
        int h = eg >> 6, e = eg & 63;
        const float* Sh = S + (size_t)h * 4096;
        const float* ah = a + h * dh_;
        float acc = 0.0f;
        #pragma unroll 8
        for (int dd = 0; dd < 64; ++dd) acc += ah[dd] * Sh[dd * 64 + e];
        out[(size_t)row * D_ + eg] = xo[eg] + acc;
    }
}

// ---------------------------------------------------------------------------
extern "C" void kernel_launch(void* const* d_in, const int* in_sizes, int n_in,
                              void* d_out, int out_size, void* d_ws, size_t ws_size,
                              hipStream_t stream) {
    const float* x_in  = (const float*)d_in[0];
    const float* ln_w  = (const float*)d_in[1];
    const float* fc_w  = (const float*)d_in[2];
    const float* fc2_w = (const float*)d_in[3];
    const float* fc2_b = (const float*)d_in[4];
    const float* var_w = (const float*)d_in[5];
    const float* q_w   = (const float*)d_in[6];
    const float* v_w   = (const float*)d_in[7];
    const float* qn_w  = (const float*)d_in[8];
    const float* vn_w  = (const float*)d_in[9];
    const float* LU    = (const float*)d_in[10];
    float* out = (float*)d_out;
    float* ws  = (float*)d_ws;

    // workspace layout (floats); gbuf dead after MLP -> reused for q/v bufs,
    // hbuf dead after var-RMS -> reused for attention layer-1 K input.
    float* xbuf  = ws;                        // BND
    float* hbuf  = ws + BND_;                 // BND
    float* gbuf  = ws + 2 * BND_;             // 4*BND (BN x 2048)
    float* xorig = ws + 6 * BND_;             // BND
    float* arbuf = ws + 7 * BND_;             // BND/2
    float* Sbuf  = ws + 7 * BND_ + BND_ / 2;  // H*64*64
    float* qbuf  = gbuf;                      // 2*BND (NL layers)
    float* vbuf  = gbuf + 2 * BND_;           // 2*BND
    float* xabuf = hbuf;                      // BND

    dim3 blk(256);
    dim3 g_rows(BN_);
    dim3 g_fc1(D4_ / 128, BN_ / 128);          // 16 x 32 = 512 blocks
    dim3 g_fc2(D_ / 128, BN_ / 128, 4);        // split-K x4 = 512 blocks
    dim3 g_init(BND_ / 1024);
    dim3 g_qv(D_ / 128, BN_ / 128, 4);         // (layer, q/v) = 512 blocks
    dim3 g_hrms(BN_ * H_ / 4);

    // --- pre-MLP stack ---
    for (int i = 0; i < NL_; ++i) {
        const float* src = (i == 0) ? x_in : xbuf;
        rms_kernel<<<g_rows, blk, 0, stream>>>(src, ln_w + i * D_, hbuf, 1e-5f);
        mfma_gemm<1><<<g_fc1, blk, 0, stream>>>(hbuf, fc_w + (size_t)i * D_ * D4_,
                                                gbuf, D_, D4_, D_);
        fc2init_kernel<<<g_init, blk, 0, stream>>>((i == 0) ? x_in : nullptr,
                                                   fc2_b + i * D_, xbuf);
        mfma_gemm<2><<<g_fc2, blk, 0, stream>>>(gbuf, fc2_w + (size_t)i * D4_ * D_,
                                                xbuf, D4_, D_, 512);
    }

    // --- var RMS -> x_orig ---
    rms_kernel<<<g_rows, blk, 0, stream>>>(xbuf, var_w, xorig, 1e-5f);

    // --- S = L @ U ---
    smat_kernel<<<dim3(H_), blk, 0, stream>>>(LU, Sbuf);

    // --- all 4 Q/V projections in ONE launch + per-head RMS passes ---
    qv_mfma_gemm<<<g_qv, blk, 0, stream>>>(xorig, q_w, v_w, qbuf, vbuf);
    for (int i = 0; i < NL_; ++i) {
        headrms_kernel<<<g_hrms, blk, 0, stream>>>(qbuf + (size_t)i * BND_,
                                                   qn_w + i * H_ * dh_, 1e-8f);
        headrms_kernel<<<g_hrms, blk, 0, stream>>>(vbuf + (size_t)i * BND_,
                                                   vn_w + i * H_ * dh_, 1e-8f);
    }

    // --- stacked linear attention (layer 1's K is layer 0's output) ---
    dim3 g_attn(B_ * H_);
    attn_kernel<1><<<g_attn, blk, 0, stream>>>(xorig, qbuf, vbuf, xabuf, arbuf);
    attn_kernel<0><<<g_attn, blk, 0, stream>>>(xabuf, qbuf + BND_, vbuf + BND_,
                                               nullptr, arbuf);

    // --- final: x_orig odd rows + attn_res @ S ---
    final_kernel<<<dim3(B_ * N_ / 2), blk, 0, stream>>>(xorig, arbuf, Sbuf, out);
}